// Round 16
// baseline (3682.723 us; speedup 1.0000x reference)
//
#include <hip/hip_runtime.h>
#include <hip/hip_bf16.h>

typedef __attribute__((ext_vector_type(8)))  short short8;
typedef __attribute__((ext_vector_type(16))) float f32x16;
typedef __attribute__((ext_vector_type(4)))  unsigned int uint4v;

#define TSTEPS 1024
#define BATCH  128
#define NIN    256
#define NHID   512
#define GM     4
#define MBLK   32
#define XPSTR  528     // x row-PAIR stride in bf16 elems (1056B)
#define XBUF   8448    // elems per x buffer (16 pairs)

// ws layout (zeroed each launch):
#define DSLOT  32768   // per (group,slot) fragment data: 32 kb x 32 row x 2 half x 16B
#define DGRP   65536   // per group (2 slots)
#define TAGOFF 262144  // tag region base
#define TGRP   8192    // per group (2 slots x 4096)
#define TSLOT  4096    // 64 tags x 64B
#define ZBYTES 294912

__device__ __forceinline__ unsigned short f2bf(float f) {
  unsigned int u = __builtin_bit_cast(unsigned int, f);
  u += 0x7fffu + ((u >> 16) & 1u);
  return (unsigned short)(u >> 16);
}

__device__ __forceinline__ unsigned long long pack4(float a, float b, float c, float d) {
  return (unsigned long long)f2bf(a)
       | ((unsigned long long)f2bf(b) << 16)
       | ((unsigned long long)f2bf(c) << 32)
       | ((unsigned long long)f2bf(d) << 48);
}

__device__ __forceinline__ float sigf(float x) {
  return 1.0f / (1.0f + __expf(-x));
}
__device__ __forceinline__ float tanh_fast(float x) {
  x = fminf(fmaxf(x, -15.0f), 15.0f);
  float e = __expf(2.0f * x);
  return (e - 1.0f) / (e + 1.0f);
}

// Zero fragment data (256KB) + tags (32KB): slot0 data=0 == h_0, tags=0 == epoch 0.
__global__ void init_ws_kernel(unsigned long long* w) {
  int idx = blockIdx.x * blockDim.x + threadIdx.x;
  for (int i = idx; i < ZBYTES / 8; i += 16384) w[i] = 0ull;
}

// One-time x fp32 -> bf16 (linear layout; consumed by global_load_lds).
__global__ void convert_x_kernel(const float* __restrict__ x, unsigned short* __restrict__ xbf) {
  const int N4 = TSTEPS * BATCH * NIN / 4;
  for (int i = blockIdx.x * blockDim.x + threadIdx.x; i < N4; i += gridDim.x * blockDim.x) {
    float4 f = *(const float4*)(x + (size_t)i * 4);
    *(unsigned long long*)(xbf + (size_t)i * 4) = pack4(f.x, f.y, f.z, f.w);
  }
}

#define MFMA(va, fb, acc) \
  acc = __builtin_amdgcn_mfma_f32_32x32x16_bf16(va, fb, acc, 0, 0, 0)
#define MF(r, b, acc) \
  acc = __builtin_amdgcn_mfma_f32_32x32x16_bf16(__builtin_bit_cast(short8, r), b, acc, 0, 0, 0)

// device scope (sc1): cross-XCD coherent
#define HISSUE(r, kb_) \
  asm volatile("global_load_dwordx4 %0, %1, off sc1" : "=v"(r) : "v"(hb + (kb_) * 1024))
#define VMW(n) do { asm volatile("s_waitcnt vmcnt(" #n ")" ::: "memory"); \
  __builtin_amdgcn_sched_barrier(0); } while (0)

#define CONS8(r0,r1,r2,r3,r4,r5,r6,r7, B) \
  MF(r0, bfrag[(B)+0], a0); MF(r1, bfrag[(B)+1], a1); \
  MF(r2, bfrag[(B)+2], a2); MF(r3, bfrag[(B)+3], a3); \
  MF(r4, bfrag[(B)+4], a0); MF(r5, bfrag[(B)+5], a1); \
  MF(r6, bfrag[(B)+6], a2); MF(r7, bfrag[(B)+7], a3);

template <int USE_DMA>
__global__ __launch_bounds__(256, 1) void lstm_persistent(
    const float* __restrict__ x,            // fp32 x (MODE0 only)
    const unsigned short* __restrict__ xbf, // bf16 x (MODE1 only)
    const float* __restrict__ Wih,
    const float* __restrict__ Whh,
    const float* __restrict__ bih,
    const float* __restrict__ bhh,
    float* __restrict__ out,                // h, h, c
    char* __restrict__ ws)
{
  const int tid  = threadIdx.x;
  const int lane = tid & 63;
  const int wv   = tid >> 6;
  const int gm   = blockIdx.x & (GM - 1);
  const int gh   = blockIdx.x >> 2;
  const int m0   = gm * MBLK;
  const int hc0  = gh * 32;

  __shared__ short x_flat[3 * XBUF];
  __shared__ float z_lds[2][4][MBLK][36];   // double-buffered z

  // ---------------- W fragments -> registers ----------------
  const int ncol = lane & 31;
  const int h5   = lane >> 5;
  const int arow = lane & 31;
  const int kg   = h5 * 8;
  const int gate = ncol >> 3;
  const int wrow = gate * NHID + hc0 + wv * 8 + (ncol & 7);

  short8 bfrag[48];
#pragma unroll
  for (int kb = 0; kb < 48; ++kb) {
    const float* src = (kb < 16)
        ? (Wih + (size_t)wrow * NIN  + (kb * 16 + kg))
        : (Whh + (size_t)wrow * NHID + (kb * 16 + kg - NIN));
    float4 f0 = *(const float4*)src;
    float4 f1 = *(const float4*)(src + 4);
    short8 b;
    b[0] = (short)f2bf(f0.x); b[1] = (short)f2bf(f0.y);
    b[2] = (short)f2bf(f0.z); b[3] = (short)f2bf(f0.w);
    b[4] = (short)f2bf(f1.x); b[5] = (short)f2bf(f1.y);
    b[6] = (short)f2bf(f1.z); b[7] = (short)f2bf(f1.w);
    bfrag[kb] = b;
  }
  const float bias_c = bih[wrow] + bhh[wrow];

  // gate mapping (R6/R9): thread owns (row tid>>3, cols (tid&7)*4..+3)
  const int grow = tid >> 3;
  const int c4   = (tid & 7) * 4;
  float creg[4] = {0.0f, 0.0f, 0.0f, 0.0f};

  char* db = ws + gm * DGRP;
  char* tb = ws + TAGOFF + gm * TGRP;
  const int frago = (lane & 31) * 32 + h5 * 16;   // consumer within-kb offset
  const int mytag = gh * 4 + wv;
  // producer store offset within slot (R12-verified)
  const int pso = (2 * gh + (c4 >> 4)) * 1024 + grow * 32 + ((c4 >> 3) & 1) * 16 + (c4 & 7) * 2;

#define XLOAD(i, v) { int u = tid + 256 * (i); \
    v = *(const float4*)(xt + (size_t)(u >> 6) * NIN + (u & 63) * 4); }
#define XPACK(bb, i, v) { int u = tid + 256 * (i); int r = u >> 6; int hc = u & 63; \
    *(unsigned long long*)&x_flat[(bb) * XBUF + (r >> 1) * XPSTR + (r & 1) * NIN + hc * 4] \
        = pack4(v.x, v.y, v.z, v.w); }
#define XDMA(tt, bb) { \
    const unsigned short* gsrc = xbf + ((size_t)(tt) * BATCH + m0) * NIN; \
    short* ldst = x_flat + (bb) * XBUF; \
    _Pragma("unroll") \
    for (int j = 0; j < 4; ++j) { \
      int ck = 4 * wv + j; \
      const unsigned short* gp = gsrc + (size_t)(2 * ck + h5) * NIN + (lane & 31) * 8; \
      __builtin_amdgcn_global_load_lds((const unsigned int*)gp, \
          (unsigned int*)(ldst + ck * XPSTR), 16, 0, 0); \
    } }

  f32x16 a0, a1, a2, a3;
  float4 xv0, xv1, xv2, xv3, xv4, xv5, xv6, xv7;

  // ---------------- prologue: stage x0..x2, compute zx_0 ----------------
  if (USE_DMA) {
    XDMA(0, 0) XDMA(1, 1) XDMA(2, 2)
    asm volatile("s_waitcnt vmcnt(0)" ::: "memory");
  } else {
    { const float* xt = x + (size_t)m0 * NIN;
      XLOAD(0, xv0) XLOAD(1, xv1) XLOAD(2, xv2) XLOAD(3, xv3)
      XLOAD(4, xv4) XLOAD(5, xv5) XLOAD(6, xv6) XLOAD(7, xv7)
      XPACK(0, 0, xv0) XPACK(0, 1, xv1) XPACK(0, 2, xv2) XPACK(0, 3, xv3)
      XPACK(0, 4, xv4) XPACK(0, 5, xv5) XPACK(0, 6, xv6) XPACK(0, 7, xv7) }
    { const float* xt = x + ((size_t)BATCH + m0) * NIN;
      XLOAD(0, xv0) XLOAD(1, xv1) XLOAD(2, xv2) XLOAD(3, xv3)
      XLOAD(4, xv4) XLOAD(5, xv5) XLOAD(6, xv6) XLOAD(7, xv7)
      XPACK(1, 0, xv0) XPACK(1, 1, xv1) XPACK(1, 2, xv2) XPACK(1, 3, xv3)
      XPACK(1, 4, xv4) XPACK(1, 5, xv5) XPACK(1, 6, xv6) XPACK(1, 7, xv7) }
  }
  __syncthreads();
  a0 = (f32x16)bias_c; a1 = (f32x16)0.0f; a2 = (f32x16)0.0f; a3 = (f32x16)0.0f;
  {
    const short* xrow = x_flat + (arow >> 1) * XPSTR + (arow & 1) * NIN + kg;
#pragma unroll
    for (int kb = 0; kb < 16; kb += 4) {
      MFMA(*(const short8*)(xrow + (kb + 0) * 16), bfrag[kb + 0], a0);
      MFMA(*(const short8*)(xrow + (kb + 1) * 16), bfrag[kb + 1], a1);
      MFMA(*(const short8*)(xrow + (kb + 2) * 16), bfrag[kb + 2], a2);
      MFMA(*(const short8*)(xrow + (kb + 3) * 16), bfrag[kb + 3], a3);
    }
  }

  int tmod = 0;   // t % 3
  for (int t = 0; t < TSTEPS; ++t) {
    // -------- 1. light tag poll: lane i watches tag i (4B/lane per check) ----------
    {
      const char* tp = tb + (t & 1) * TSLOT + lane * 64;
      unsigned int tv;
      do {
        asm volatile("global_load_dword %0, %1, off sc1" : "=v"(tv) : "v"(tp));
        asm volatile("s_waitcnt vmcnt(0)" ::: "memory");
      } while (!__all((int)(tv >= (unsigned int)t)));
      __builtin_amdgcn_sched_barrier(0);
    }

    // -------- 2. h A-fragments LLC->registers, 24-deep rolling pipeline ------------
    {
      const char* hb = db + (t & 1) * DSLOT + frago;
      uint4v h0, h1, h2, h3, h4, h5v, h6, h7;
      uint4v h8, h9, h10, h11, h12, h13, h14, h15;
      uint4v h16, h17, h18, h19, h20, h21, h22, h23;
      HISSUE(h0, 0);   HISSUE(h1, 1);   HISSUE(h2, 2);   HISSUE(h3, 3);
      HISSUE(h4, 4);   HISSUE(h5v, 5);  HISSUE(h6, 6);   HISSUE(h7, 7);
      HISSUE(h8, 8);   HISSUE(h9, 9);   HISSUE(h10, 10); HISSUE(h11, 11);
      HISSUE(h12, 12); HISSUE(h13, 13); HISSUE(h14, 14); HISSUE(h15, 15);
      HISSUE(h16, 16); HISSUE(h17, 17); HISSUE(h18, 18); HISSUE(h19, 19);
      HISSUE(h20, 20); HISSUE(h21, 21); HISSUE(h22, 22); HISSUE(h23, 23);
      VMW(16);                                   // h0..h7 ready
      CONS8(h0, h1, h2, h3, h4, h5v, h6, h7, 16)
      HISSUE(h0, 24);  HISSUE(h1, 25);  HISSUE(h2, 26);  HISSUE(h3, 27);
      HISSUE(h4, 28);  HISSUE(h5v, 29); HISSUE(h6, 30);  HISSUE(h7, 31);
      VMW(16);                                   // h8..h15 ready
      CONS8(h8, h9, h10, h11, h12, h13, h14, h15, 24)
      VMW(8);                                    // h16..h23 ready
      CONS8(h16, h17, h18, h19, h20, h21, h22, h23, 32)
      VMW(0);                                    // kb 24..31 ready
      CONS8(h0, h1, h2, h3, h4, h5v, h6, h7, 40)
    }

    // -------- 3. MODE0: issue x_{t+2} register loads (latency hides below) ---------
    if (!USE_DMA && t + 2 < TSTEPS) {
      const float* xt = x + ((size_t)(t + 2) * BATCH + m0) * NIN;
      XLOAD(0, xv0) XLOAD(1, xv1) XLOAD(2, xv2) XLOAD(3, xv3)
      XLOAD(4, xv4) XLOAD(5, xv5) XLOAD(6, xv6) XLOAD(7, xv7)
    }

    // -------- 4. z -> LDS (slot t&1), the ONLY barrier ------------------------------
    {
      f32x16 acc = (a0 + a1) + (a2 + a3);
#pragma unroll
      for (int r = 0; r < 16; ++r) {
        int zr = (r & 3) + 8 * (r >> 2) + 4 * h5;
        z_lds[t & 1][wv][zr][ncol] = acc[r];
      }
    }
    __syncthreads();

    // -------- 5. gates + cell update; publish fragment store + per-wave tag --------
    {
      const int wz = c4 >> 3;
      const int cc = c4 & 7;
      const float* zrow = &z_lds[t & 1][wz][grow][0];
      float4 vi = *(const float4*)&zrow[ 0 + cc];
      float4 vf = *(const float4*)&zrow[ 8 + cc];
      float4 vg = *(const float4*)&zrow[16 + cc];
      float4 vo = *(const float4*)&zrow[24 + cc];
      float zi[4] = {vi.x, vi.y, vi.z, vi.w};
      float zf[4] = {vf.x, vf.y, vf.z, vf.w};
      float zg[4] = {vg.x, vg.y, vg.z, vg.w};
      float zo[4] = {vo.x, vo.y, vo.z, vo.w};
      float hnv[4];
#pragma unroll
      for (int u = 0; u < 4; ++u) {
        float iv = sigf(zi[u]);
        float fv = sigf(zf[u]);
        float gv = tanh_fast(zg[u]);
        float ov = sigf(zo[u]);
        float cn = fv * creg[u] + iv * gv;
        creg[u] = cn;
        hnv[u] = ov * tanh_fast(cn);
      }
      if (t == TSTEPS - 1) {
        size_t o = (size_t)(m0 + grow) * NHID + hc0 + c4;
        float4 hq; hq.x = hnv[0]; hq.y = hnv[1]; hq.z = hnv[2]; hq.w = hnv[3];
        float4 cq; cq.x = creg[0]; cq.y = creg[1]; cq.z = creg[2]; cq.w = creg[3];
        *(float4*)&out[o]          = hq;
        *(float4*)&out[65536 + o]  = hq;
        *(float4*)&out[131072 + o] = cq;
      } else {
        // 8B fragment-layout data store -> drain -> per-wave tag (R12-proven order)
        unsigned long long hp = pack4(hnv[0], hnv[1], hnv[2], hnv[3]);
        char* pd = db + ((t + 1) & 1) * DSLOT + pso;
        asm volatile("global_store_dwordx2 %0, %1, off sc1"
                     :: "v"(pd), "v"(hp) : "memory");
        asm volatile("s_waitcnt vmcnt(0)" ::: "memory");
        if (lane == 0) {
          unsigned int tg = (unsigned int)(t + 1);
          char* tp = tb + ((t + 1) & 1) * TSLOT + mytag * 64;
          asm volatile("global_store_dword %0, %1, off sc1"
                       :: "v"(tp), "v"(tg) : "memory");
        }
      }
    }

    if (t < TSTEPS - 1) {
      // -------- 6. refill x pipeline (off the publish path) -------------------------
      if (USE_DMA) {
        if (t + 3 < TSTEPS) { XDMA(t + 3, tmod) }
      } else if (t + 2 < TSTEPS) {
        int pb = tmod + 2; if (pb >= 3) pb -= 3;
        XPACK(pb, 0, xv0) XPACK(pb, 1, xv1) XPACK(pb, 2, xv2) XPACK(pb, 3, xv3)
        XPACK(pb, 4, xv4) XPACK(pb, 5, xv5) XPACK(pb, 6, xv6) XPACK(pb, 7, xv7)
      }
      // -------- 7. zx_{t+1} = bias + x-part (overlaps other blocks' phases) ---------
      int nb = tmod + 1; if (nb >= 3) nb -= 3;
      a0 = (f32x16)bias_c; a1 = (f32x16)0.0f; a2 = (f32x16)0.0f; a3 = (f32x16)0.0f;
      const short* xrow = x_flat + nb * XBUF + (arow >> 1) * XPSTR + (arow & 1) * NIN + kg;
#pragma unroll
      for (int kb = 0; kb < 16; kb += 4) {
        MFMA(*(const short8*)(xrow + (kb + 0) * 16), bfrag[kb + 0], a0);
        MFMA(*(const short8*)(xrow + (kb + 1) * 16), bfrag[kb + 1], a1);
        MFMA(*(const short8*)(xrow + (kb + 2) * 16), bfrag[kb + 2], a2);
        MFMA(*(const short8*)(xrow + (kb + 3) * 16), bfrag[kb + 3], a3);
      }
    }
    tmod = tmod + 1; if (tmod >= 3) tmod = 0;
  }
#undef XLOAD
#undef XPACK
#undef XDMA
}

extern "C" void kernel_launch(void* const* d_in, const int* in_sizes, int n_in,
                              void* d_out, int out_size, void* d_ws, size_t ws_size,
                              hipStream_t stream) {
  const float* x   = (const float*)d_in[0];
  const float* Wih = (const float*)d_in[1];
  const float* Whh = (const float*)d_in[2];
  const float* bih = (const float*)d_in[3];
  const float* bhh = (const float*)d_in[4];
  float* out = (float*)d_out;

  char* ws = (char*)d_ws;
  unsigned short* xbf = (unsigned short*)(ws + (1 << 20));   // 64 MB bf16 x

  size_t need = (size_t)(1 << 20) + (size_t)TSTEPS * BATCH * NIN * 2;
  bool dma = ws_size >= need;

  hipLaunchKernelGGL(init_ws_kernel, dim3(64), dim3(256), 0, stream,
                     (unsigned long long*)ws);
  if (dma) {
    hipLaunchKernelGGL(convert_x_kernel, dim3(8192), dim3(256), 0, stream, x, xbf);
    hipLaunchKernelGGL((lstm_persistent<1>), dim3(64), dim3(256), 0, stream,
                       x, xbf, Wih, Whh, bih, bhh, out, ws);
  } else {
    hipLaunchKernelGGL((lstm_persistent<0>), dim3(64), dim3(256), 0, stream,
                       x, xbf, Wih, Whh, bih, bhh, out, ws);
  }
}

// Round 18
// 3387.950 us; speedup vs baseline: 1.0870x; 1.0870x over previous
//
#include <hip/hip_runtime.h>
#include <hip/hip_bf16.h>

typedef __attribute__((ext_vector_type(8)))  short short8;
typedef __attribute__((ext_vector_type(16))) float f32x16;
typedef __attribute__((ext_vector_type(4)))  unsigned int uint4v;

#define TSTEPS 1024
#define BATCH  128
#define NIN    256
#define NHID   512
#define GM     4
#define MBLK   32
#define XPSTR  528     // x row-PAIR stride in bf16 elems (1056B)
#define XBUF   8448    // elems per x buffer (16 pairs)
#define HSTR   520     // h row stride in bf16 elems (1040B)
#define HBUF   16640   // elems per h buffer (32*520)

__device__ __forceinline__ unsigned short f2bf(float f) {
  unsigned int u = __builtin_bit_cast(unsigned int, f);
  u += 0x7fffu + ((u >> 16) & 1u);
  return (unsigned short)(u >> 16);
}

__device__ __forceinline__ unsigned long long pack4(float a, float b, float c, float d) {
  return (unsigned long long)f2bf(a)
       | ((unsigned long long)f2bf(b) << 16)
       | ((unsigned long long)f2bf(c) << 32)
       | ((unsigned long long)f2bf(d) << 48);
}

__device__ __forceinline__ float sigf(float x) {
  return 1.0f / (1.0f + __expf(-x));
}
__device__ __forceinline__ float tanh_fast(float x) {
  x = fminf(fmaxf(x, -15.0f), 15.0f);
  float e = __expf(2.0f * x);
  return (e - 1.0f) / (e + 1.0f);
}

// Zero the tagged h exchange buffer: [4 groups][2 slots][4096 cells][16B] = 512KB.
// Slot0 tag=0 + zero data == valid h_0 = 0 for the t=0 poll.
__global__ void init_ws_kernel(unsigned long long* tbuf) {
  int idx = blockIdx.x * blockDim.x + threadIdx.x;
  for (int i = idx; i < 65536; i += 16384) tbuf[i] = 0ull;
}

// One-time x fp32 -> bf16 (linear layout, same [t][m][c] order).
__global__ void convert_x_kernel(const float* __restrict__ x, unsigned short* __restrict__ xbf) {
  const int N4 = TSTEPS * BATCH * NIN / 4;
  for (int i = blockIdx.x * blockDim.x + threadIdx.x; i < N4; i += gridDim.x * blockDim.x) {
    float4 f = *(const float4*)(x + (size_t)i * 4);
    *(unsigned long long*)(xbf + (size_t)i * 4) = pack4(f.x, f.y, f.z, f.w);
  }
}

#define MFMA(va, fb, acc) \
  acc = __builtin_amdgcn_mfma_f32_32x32x16_bf16(va, fb, acc, 0, 0, 0)

// DEVICE scope (sc1 only): cross-XCD coherent (R15-proven).
#define CLOAD(cv, off) \
  asm volatile("global_load_dwordx4 %0, %1, off sc1" : "=v"(cv) : "v"(rb + (off)))

template <int USE_DMA>
__global__ __launch_bounds__(256, 1) void lstm_persistent(
    const float* __restrict__ x,            // fp32 x (MODE0 only)
    const unsigned short* __restrict__ xbf, // bf16 x (MODE1 only)
    const float* __restrict__ Wih,
    const float* __restrict__ Whh,
    const float* __restrict__ bih,
    const float* __restrict__ bhh,
    float* __restrict__ out,                // h, h, c
    char* __restrict__ tbuf)                // [4][2][4096] 16B tagged cells
{
  const int tid  = threadIdx.x;
  const int lane = tid & 63;
  const int wv   = tid >> 6;
  const int gm   = blockIdx.x & (GM - 1);
  const int gh   = blockIdx.x >> 2;
  const int m0   = gm * MBLK;
  const int hc0  = gh * 32;

  __shared__ short x_flat[3 * XBUF];
  __shared__ short h_flat[2 * HBUF];
  __shared__ float z_lds[4][MBLK][36];

  // ---------------- W fragments -> registers ----------------
  const int ncol = lane & 31;
  const int h5   = lane >> 5;
  const int arow = lane & 31;
  const int kg   = h5 * 8;
  const int gate = ncol >> 3;
  const int wrow = gate * NHID + hc0 + wv * 8 + (ncol & 7);

  short8 bfrag[48];
#pragma unroll
  for (int kb = 0; kb < 48; ++kb) {
    const float* src = (kb < 16)
        ? (Wih + (size_t)wrow * NIN  + (kb * 16 + kg))
        : (Whh + (size_t)wrow * NHID + (kb * 16 + kg - NIN));
    float4 f0 = *(const float4*)src;
    float4 f1 = *(const float4*)(src + 4);
    short8 b;
    b[0] = (short)f2bf(f0.x); b[1] = (short)f2bf(f0.y);
    b[2] = (short)f2bf(f0.z); b[3] = (short)f2bf(f0.w);
    b[4] = (short)f2bf(f1.x); b[5] = (short)f2bf(f1.y);
    b[6] = (short)f2bf(f1.z); b[7] = (short)f2bf(f1.w);
    bfrag[kb] = b;
  }
  const float bias_c = bih[wrow] + bhh[wrow];

  // gate mapping (R6/R9): thread owns (row tid>>3, cols (tid&7)*4..+3)
  const int grow = tid >> 3;
  const int c4   = (tid & 7) * 4;
  float creg[4] = {0.0f, 0.0f, 0.0f, 0.0f};

  const char* tb = tbuf + (size_t)gm * 131072;          // [slot][4096 cells]
  const int  myci = grow * 128 + (hc0 >> 2) + (tid & 7); // producer cell index

#define XLOAD(i, v) { int u = tid + 256 * (i); \
    v = *(const float4*)(xt + (size_t)(u >> 6) * NIN + (u & 63) * 4); }
#define XPACK(bb, i, v) { int u = tid + 256 * (i); int r = u >> 6; int hc = u & 63; \
    *(unsigned long long*)&x_flat[(bb) * XBUF + (r >> 1) * XPSTR + (r & 1) * NIN + hc * 4] \
        = pack4(v.x, v.y, v.z, v.w); }
#define XDMA(tt, bb) { \
    const unsigned short* gsrc = xbf + ((size_t)(tt) * BATCH + m0) * NIN; \
    short* ldst = x_flat + (bb) * XBUF; \
    _Pragma("unroll") \
    for (int j = 0; j < 4; ++j) { \
      int ck = 4 * wv + j; \
      const unsigned short* gp = gsrc + (size_t)(2 * ck + h5) * NIN + (lane & 31) * 8; \
      __builtin_amdgcn_global_load_lds((const unsigned int*)gp, \
          (unsigned int*)(ldst + ck * XPSTR), 16, 0, 0); \
    } }

  f32x16 a0, a1, a2, a3;
  float4 xv0, xv1, xv2, xv3, xv4, xv5, xv6, xv7;

  // ---------------- prologue: stage x0..x2, compute zx_0 ----------------
  if (USE_DMA) {
    XDMA(0, 0) XDMA(1, 1) XDMA(2, 2)
    asm volatile("s_waitcnt vmcnt(0)" ::: "memory");
  } else {
    { const float* xt = x + (size_t)m0 * NIN;
      XLOAD(0, xv0) XLOAD(1, xv1) XLOAD(2, xv2) XLOAD(3, xv3)
      XLOAD(4, xv4) XLOAD(5, xv5) XLOAD(6, xv6) XLOAD(7, xv7)
      XPACK(0, 0, xv0) XPACK(0, 1, xv1) XPACK(0, 2, xv2) XPACK(0, 3, xv3)
      XPACK(0, 4, xv4) XPACK(0, 5, xv5) XPACK(0, 6, xv6) XPACK(0, 7, xv7) }
    { const float* xt = x + ((size_t)BATCH + m0) * NIN;
      XLOAD(0, xv0) XLOAD(1, xv1) XLOAD(2, xv2) XLOAD(3, xv3)
      XLOAD(4, xv4) XLOAD(5, xv5) XLOAD(6, xv6) XLOAD(7, xv7)
      XPACK(1, 0, xv0) XPACK(1, 1, xv1) XPACK(1, 2, xv2) XPACK(1, 3, xv3)
      XPACK(1, 4, xv4) XPACK(1, 5, xv5) XPACK(1, 6, xv6) XPACK(1, 7, xv7) }
  }
  __syncthreads();
  a0 = (f32x16)bias_c; a1 = (f32x16)0.0f; a2 = (f32x16)0.0f; a3 = (f32x16)0.0f;
  {
    const short* xrow = x_flat + (arow >> 1) * XPSTR + (arow & 1) * NIN + kg;
#pragma unroll
    for (int kb = 0; kb < 16; kb += 4) {
      MFMA(*(const short8*)(xrow + (kb + 0) * 16), bfrag[kb + 0], a0);
      MFMA(*(const short8*)(xrow + (kb + 1) * 16), bfrag[kb + 1], a1);
      MFMA(*(const short8*)(xrow + (kb + 2) * 16), bfrag[kb + 2], a2);
      MFMA(*(const short8*)(xrow + (kb + 3) * 16), bfrag[kb + 3], a3);
    }
  }

  int tmod = 0;   // t % 3
  for (int t = 0; t < TSTEPS; ++t) {
    // -------- 1+2. tagged poll: detect and h data arrive in the SAME loads ----------
    {
      const char* rb = tb + (size_t)(t & 1) * 65536 + (size_t)tid * 16;
      const unsigned int tg = (unsigned int)t;
      uint4v c0, c1, c2, c3, c4v, c5, c6, c7, c8, c9, c10, c11, c12, c13, c14, c15;
      int ok;
      do {
        CLOAD(c0,  0 * 4096); CLOAD(c1,  1 * 4096); CLOAD(c2,  2 * 4096);
        CLOAD(c3,  3 * 4096); CLOAD(c4v, 4 * 4096); CLOAD(c5,  5 * 4096);
        CLOAD(c6,  6 * 4096); CLOAD(c7,  7 * 4096); CLOAD(c8,  8 * 4096);
        CLOAD(c9,  9 * 4096); CLOAD(c10, 10 * 4096); CLOAD(c11, 11 * 4096);
        CLOAD(c12, 12 * 4096); CLOAD(c13, 13 * 4096); CLOAD(c14, 14 * 4096);
        CLOAD(c15, 15 * 4096);
        asm volatile("s_waitcnt vmcnt(0)" ::: "memory");
        ok = (c0.z == tg) & (c1.z == tg) & (c2.z == tg) & (c3.z == tg)
           & (c4v.z == tg) & (c5.z == tg) & (c6.z == tg) & (c7.z == tg)
           & (c8.z == tg) & (c9.z == tg) & (c10.z == tg) & (c11.z == tg)
           & (c12.z == tg) & (c13.z == tg) & (c14.z == tg) & (c15.z == tg);
      } while (!__all(ok));
      __builtin_amdgcn_sched_barrier(0);
      short* hdst = h_flat + (t & 1) * HBUF;
#define HPUT(j, cv) { int ci = tid + 256 * (j); \
      *(unsigned long long*)&hdst[(ci >> 7) * HSTR + (ci & 127) * 4] = \
          (unsigned long long)cv.x | ((unsigned long long)cv.y << 32); }
      HPUT(0, c0)  HPUT(1, c1)  HPUT(2, c2)  HPUT(3, c3)
      HPUT(4, c4v) HPUT(5, c5)  HPUT(6, c6)  HPUT(7, c7)
      HPUT(8, c8)  HPUT(9, c9)  HPUT(10, c10) HPUT(11, c11)
      HPUT(12, c12) HPUT(13, c13) HPUT(14, c14) HPUT(15, c15)
#undef HPUT
    }
    __syncthreads();                       // (a)

    // -------- 3. MODE0: issue x_{t+2} register loads ---------------------------------
    if (!USE_DMA && t + 2 < TSTEPS) {
      const float* xt = x + ((size_t)(t + 2) * BATCH + m0) * NIN;
      XLOAD(0, xv0) XLOAD(1, xv1) XLOAD(2, xv2) XLOAD(3, xv3)
      XLOAD(4, xv4) XLOAD(5, xv5) XLOAD(6, xv6) XLOAD(7, xv7)
    }

    // -------- 4. 32 h-part MFMAs accumulate onto zx_t --------------------------------
    {
      const short* hrow = h_flat + (t & 1) * HBUF + arow * HSTR + kg;
#pragma unroll
      for (int kb = 0; kb < 32; kb += 4) {
        MFMA(*(const short8*)(hrow + (kb + 0) * 16), bfrag[16 + kb + 0], a0);
        MFMA(*(const short8*)(hrow + (kb + 1) * 16), bfrag[16 + kb + 1], a1);
        MFMA(*(const short8*)(hrow + (kb + 2) * 16), bfrag[16 + kb + 2], a2);
        MFMA(*(const short8*)(hrow + (kb + 3) * 16), bfrag[16 + kb + 3], a3);
      }
    }

    // -------- 5. z -> LDS, barrier (b) ----------------------------------------------
    {
      f32x16 acc = (a0 + a1) + (a2 + a3);
#pragma unroll
      for (int r = 0; r < 16; ++r) {
        int zr = (r & 3) + 8 * (r >> 2) + 4 * h5;
        z_lds[wv][zr][ncol] = acc[r];
      }
    }
    __syncthreads();                       // (b)

    // -------- 6. gates + cell update; publish via ONE tagged store -------------------
    {
      const int wz = c4 >> 3;
      const int cc = c4 & 7;
      const float* zrow = &z_lds[wz][grow][0];
      float4 vi = *(const float4*)&zrow[ 0 + cc];
      float4 vf = *(const float4*)&zrow[ 8 + cc];
      float4 vg = *(const float4*)&zrow[16 + cc];
      float4 vo = *(const float4*)&zrow[24 + cc];
      float zi[4] = {vi.x, vi.y, vi.z, vi.w};
      float zf[4] = {vf.x, vf.y, vf.z, vf.w};
      float zg[4] = {vg.x, vg.y, vg.z, vg.w};
      float zo[4] = {vo.x, vo.y, vo.z, vo.w};
      float hnv[4];
#pragma unroll
      for (int u = 0; u < 4; ++u) {
        float iv = sigf(zi[u]);
        float fv = sigf(zf[u]);
        float gv = tanh_fast(zg[u]);
        float ov = sigf(zo[u]);
        float cn = fv * creg[u] + iv * gv;
        creg[u] = cn;
        hnv[u] = ov * tanh_fast(cn);
      }
      if (t == TSTEPS - 1) {
        size_t o = (size_t)(m0 + grow) * NHID + hc0 + c4;
        float4 hq; hq.x = hnv[0]; hq.y = hnv[1]; hq.z = hnv[2]; hq.w = hnv[3];
        float4 cq; cq.x = creg[0]; cq.y = creg[1]; cq.z = creg[2]; cq.w = creg[3];
        *(float4*)&out[o]          = hq;
        *(float4*)&out[65536 + o]  = hq;
        *(float4*)&out[131072 + o] = cq;
      } else {
        unsigned long long hp = pack4(hnv[0], hnv[1], hnv[2], hnv[3]);
        uint4v sv;
        sv.x = (unsigned int)hp;
        sv.y = (unsigned int)(hp >> 32);
        sv.z = (unsigned int)(t + 1);     // tag rides WITH the data: no drain, no flag
        sv.w = 0u;
        const char* wb = tb + (size_t)((t + 1) & 1) * 65536 + (size_t)myci * 16;
        asm volatile("global_store_dwordx4 %0, %1, off sc1"
                     :: "v"(wb), "v"(sv) : "memory");
      }
    }

    if (t < TSTEPS - 1) {
      // -------- 7. refill x pipeline ------------------------------------------------
      if (USE_DMA) {
        if (t + 3 < TSTEPS) { XDMA(t + 3, tmod) }
      } else if (t + 2 < TSTEPS) {
        int pb = tmod + 2; if (pb >= 3) pb -= 3;
        XPACK(pb, 0, xv0) XPACK(pb, 1, xv1) XPACK(pb, 2, xv2) XPACK(pb, 3, xv3)
        XPACK(pb, 4, xv4) XPACK(pb, 5, xv5) XPACK(pb, 6, xv6) XPACK(pb, 7, xv7)
      }
      // -------- 8. zx_{t+1} = bias + x-part -----------------------------------------
      int nb = tmod + 1; if (nb >= 3) nb -= 3;
      a0 = (f32x16)bias_c; a1 = (f32x16)0.0f; a2 = (f32x16)0.0f; a3 = (f32x16)0.0f;
      const short* xrow = x_flat + nb * XBUF + (arow >> 1) * XPSTR + (arow & 1) * NIN + kg;
#pragma unroll
      for (int kb = 0; kb < 16; kb += 4) {
        MFMA(*(const short8*)(xrow + (kb + 0) * 16), bfrag[kb + 0], a0);
        MFMA(*(const short8*)(xrow + (kb + 1) * 16), bfrag[kb + 1], a1);
        MFMA(*(const short8*)(xrow + (kb + 2) * 16), bfrag[kb + 2], a2);
        MFMA(*(const short8*)(xrow + (kb + 3) * 16), bfrag[kb + 3], a3);
      }
    }
    tmod = tmod + 1; if (tmod >= 3) tmod = 0;
  }
#undef XLOAD
#undef XPACK
#undef XDMA
}

extern "C" void kernel_launch(void* const* d_in, const int* in_sizes, int n_in,
                              void* d_out, int out_size, void* d_ws, size_t ws_size,
                              hipStream_t stream) {
  const float* x   = (const float*)d_in[0];
  const float* Wih = (const float*)d_in[1];
  const float* Whh = (const float*)d_in[2];
  const float* bih = (const float*)d_in[3];
  const float* bhh = (const float*)d_in[4];
  float* out = (float*)d_out;

  char* tbuf = (char*)d_ws;                                            // 512 KB tagged cells
  unsigned short* xbf = (unsigned short*)((char*)d_ws + (1 << 20));    // 64 MB bf16 x

  size_t need = (size_t)(1 << 20) + (size_t)TSTEPS * BATCH * NIN * 2;
  bool dma = ws_size >= need;

  hipLaunchKernelGGL(init_ws_kernel, dim3(64), dim3(256), 0, stream,
                     (unsigned long long*)tbuf);
  if (dma) {
    hipLaunchKernelGGL(convert_x_kernel, dim3(8192), dim3(256), 0, stream, x, xbf);
    hipLaunchKernelGGL((lstm_persistent<1>), dim3(64), dim3(256), 0, stream,
                       x, xbf, Wih, Whh, bih, bhh, out, tbuf);
  } else {
    hipLaunchKernelGGL((lstm_persistent<0>), dim3(64), dim3(256), 0, stream,
                       x, xbf, Wih, Whh, bih, bhh, out, tbuf);
  }
}